// Round 3
// baseline (259.931 us; speedup 1.0000x reference)
//
#include <hip/hip_runtime.h>
#include <hip/hip_bf16.h>
#include <math.h>

typedef _Float16 half8 __attribute__((ext_vector_type(8)));
typedef float    f32x4 __attribute__((ext_vector_type(4)));

#define NPTS  50000
#define BATCH 8

// ---------------- weight prep: fp32 -> f16, pi-permuted columns ----------------
// 8 slots of [128 rows o][128 positions pos]. pos=(ks,g,j):
//   k(pos) = ks*32 + 16*(j>>2) + 4*g + (j&3),  pos = ks*32 + g*8 + j.
// This makes layer j's D-accumulator registers (after ELU+f16 pack) directly
// usable as layer j+1's B-fragment: same lane, same register -- x never
// leaves registers. Slot 0: [pe60|pad4|z32|pad32]; 1..6: deform; 7: lin1a.
__global__ void prep_weights_k(const float* __restrict__ w_lin0,
                               const float* __restrict__ w_def,
                               const float* __restrict__ w1a,
                               _Float16* __restrict__ W)
{
    int idx = blockIdx.x * blockDim.x + threadIdx.x;
    if (idx >= 8*128*128) return;
    int slot = idx >> 14;
    int o    = (idx >> 7) & 127;
    int pos  = idx & 127;
    int ks = pos >> 5, l = pos & 31, gg = l >> 3, jj = l & 7;
    int k = ks*32 + 16*(jj>>2) + 4*gg + (jj&3);
    float v = 0.f;
    if (slot == 0) {
        if (k < 60)                 v = w_lin0[o*92 + k];
        else if (k >= 64 && k < 96) v = w_lin0[o*92 + 60 + (k-64)];
    } else if (slot <= 6) {
        v = w_def[(slot-1)*16384 + o*128 + k];
    } else {
        if (o < 3) v = w1a[o*128 + k];
    }
    W[idx] = (_Float16)v;   // linear [slot][o][pos] layout, no swizzle
}

// ---------------- fused decoder: no LDS, no barriers ----------------
// 64-thread blocks (1 wave). Each wave owns 64 rows (8 n x 8 b), all 128
// features in registers for all layers. W A-fragments read straight from
// global (L2/L3-resident, 256 KB total). Waves fully independent -> free
// skew means ELU (VALU) of one wave overlaps MFMA of another.
__global__ __launch_bounds__(64, 2)
void decoder_main(const float* __restrict__ z0,
                  const float* __restrict__ cons,
                  const _Float16* __restrict__ W,
                  const float* __restrict__ w1b,
                  float* __restrict__ out)
{
    const int lane = threadIdx.x;
    const int p = lane & 15;
    const int g = lane >> 4;
    const int n0 = blockIdx.x * 8;          // 6250 * 8 == 50000 exactly

    const f32x4 Z = {0.f, 0.f, 0.f, 0.f};

    // ---- build layer-0 B-fragments in pi-position order ----
    half8 Bw[4][4];
    #pragma unroll
    for (int pt = 0; pt < 4; ++pt) {
        const int lrow = pt*16 + p;
        const int n = n0 + (lrow >> 3);
        const int b = lrow & 7;
        float c0 = cons[n*3+0], c1 = cons[n*3+1], c2 = cons[n*3+2];
        #pragma unroll
        for (int ks = 0; ks < 2; ++ks) {
            half8 h;
            #pragma unroll
            for (int j = 0; j < 8; ++j) {
                int k = ks*32 + 16*(j>>2) + 4*g + (j&3);
                float v = 0.f;
                if (k < 60) {
                    int c = k/20, rem = k%20, i = rem%10;
                    float f  = exp2f(7.f * (1.f - (float)i * (1.f/9.f)));  // const-folded
                    float cc = (c == 0) ? c0 : (c == 1) ? c1 : c2;
                    float a  = cc * f;
                    v = (rem < 10) ? __sinf(a) : __cosf(a);
                }
                h[j] = (_Float16)v;
            }
            Bw[pt][ks] = h;
        }
        half8 hz;
        #pragma unroll
        for (int j = 0; j < 8; ++j)
            hz[j] = (_Float16)z0[b*32 + 16*(j>>2) + 4*g + (j&3)];
        Bw[pt][2] = hz;
        #pragma unroll
        for (int j = 0; j < 8; ++j) Bw[pt][3][j] = (_Float16)0.f;
    }

    f32x4 acc[4][8];

    // ---- layer 0 (lin0): K = 96, ks 0..2 only ----
    {
        const unsigned char* a0 = (const unsigned char*)W + p*256 + g*16;
        half8 A[2][3];
        #pragma unroll
        for (int ks = 0; ks < 3; ++ks) A[0][ks] = *(const half8*)(a0 + ks*64);
        #pragma unroll
        for (int ft = 0; ft < 8; ++ft) {
            if (ft < 7) {
                const unsigned char* an = a0 + (ft+1)*4096;
                #pragma unroll
                for (int ks = 0; ks < 3; ++ks) A[(ft+1)&1][ks] = *(const half8*)(an + ks*64);
            }
            #pragma unroll
            for (int pt = 0; pt < 4; ++pt)
                acc[pt][ft] = __builtin_amdgcn_mfma_f32_16x16x32_f16(A[ft&1][0], Bw[pt][0], Z, 0, 0, 0);
            #pragma unroll
            for (int ks = 1; ks < 3; ++ks)
                #pragma unroll
                for (int pt = 0; pt < 4; ++pt)
                    acc[pt][ft] = __builtin_amdgcn_mfma_f32_16x16x32_f16(A[ft&1][ks], Bw[pt][ks], acc[pt][ft], 0, 0, 0);
        }
    }

    // ---- layers 1..6 (deform): pack prev acc (ELU iff prev layer was deform) ----
    for (int j = 1; j <= 6; ++j) {
        const unsigned char* a0 = (const unsigned char*)W + j*32768 + p*256 + g*16;
        half8 A[2][4];
        #pragma unroll
        for (int ks = 0; ks < 4; ++ks) A[0][ks] = *(const half8*)(a0 + ks*64);

        #pragma unroll
        for (int pt = 0; pt < 4; ++pt)
            #pragma unroll
            for (int ks = 0; ks < 4; ++ks) {
                half8 h;
                #pragma unroll
                for (int e = 0; e < 4; ++e) {
                    float v0 = acc[pt][2*ks][e];
                    float v1 = acc[pt][2*ks+1][e];
                    if (j >= 2) {
                        v0 = (v0 > 0.f) ? v0 : (__expf(v0) - 1.f);
                        v1 = (v1 > 0.f) ? v1 : (__expf(v1) - 1.f);
                    }
                    h[e]   = (_Float16)v0;
                    h[4+e] = (_Float16)v1;
                }
                Bw[pt][ks] = h;
            }

        #pragma unroll
        for (int ft = 0; ft < 8; ++ft) {
            if (ft < 7) {
                const unsigned char* an = a0 + (ft+1)*4096;
                #pragma unroll
                for (int ks = 0; ks < 4; ++ks) A[(ft+1)&1][ks] = *(const half8*)(an + ks*64);
            }
            #pragma unroll
            for (int pt = 0; pt < 4; ++pt)
                acc[pt][ft] = __builtin_amdgcn_mfma_f32_16x16x32_f16(A[ft&1][0], Bw[pt][0], Z, 0, 0, 0);
            #pragma unroll
            for (int ks = 1; ks < 4; ++ks)
                #pragma unroll
                for (int pt = 0; pt < 4; ++pt)
                    acc[pt][ft] = __builtin_amdgcn_mfma_f32_16x16x32_f16(A[ft&1][ks], Bw[pt][ks], acc[pt][ft], 0, 0, 0);
        }
    }

    // ---- pack layer-6 output with ELU ----
    #pragma unroll
    for (int pt = 0; pt < 4; ++pt)
        #pragma unroll
        for (int ks = 0; ks < 4; ++ks) {
            half8 h;
            #pragma unroll
            for (int e = 0; e < 4; ++e) {
                float v0 = acc[pt][2*ks][e];
                float v1 = acc[pt][2*ks+1][e];
                v0 = (v0 > 0.f) ? v0 : (__expf(v0) - 1.f);
                v1 = (v1 > 0.f) ? v1 : (__expf(v1) - 1.f);
                h[e]   = (_Float16)v0;
                h[4+e] = (_Float16)v1;
            }
            Bw[pt][ks] = h;
        }

    // ---- lin1a: 16 output rows (3 used), K=128 ----
    f32x4 a1[4];
    {
        const unsigned char* a0 = (const unsigned char*)W + 7*32768 + p*256 + g*16;
        half8 A[4];
        #pragma unroll
        for (int ks = 0; ks < 4; ++ks) A[ks] = *(const half8*)(a0 + ks*64);
        #pragma unroll
        for (int pt = 0; pt < 4; ++pt)
            a1[pt] = __builtin_amdgcn_mfma_f32_16x16x32_f16(A[0], Bw[pt][0], Z, 0, 0, 0);
        #pragma unroll
        for (int ks = 1; ks < 4; ++ks)
            #pragma unroll
            for (int pt = 0; pt < 4; ++pt)
                a1[pt] = __builtin_amdgcn_mfma_f32_16x16x32_f16(A[ks], Bw[pt][ks], a1[pt], 0, 0, 0);
    }

    // ---- ELU + lin1b (3x3) + stores, fully in-register (g==0 lanes) ----
    if (g == 0) {
        float b00=w1b[0],b01=w1b[1],b02=w1b[2];
        float b10=w1b[3],b11=w1b[4],b12=w1b[5];
        float b20=w1b[6],b21=w1b[7],b22=w1b[8];
        #pragma unroll
        for (int pt = 0; pt < 4; ++pt) {
            float r0 = a1[pt][0], r1 = a1[pt][1], r2 = a1[pt][2];
            r0 = (r0 > 0.f) ? r0 : (__expf(r0) - 1.f);
            r1 = (r1 > 0.f) ? r1 : (__expf(r1) - 1.f);
            r2 = (r2 > 0.f) ? r2 : (__expf(r2) - 1.f);
            int row = pt*16 + p;
            int n = n0 + (row >> 3);
            int b = row & 7;
            int obase = (b*NPTS + n)*3;
            float rv0 = b00*r0 + b01*r1 + b02*r2;
            float rv1 = b10*r0 + b11*r1 + b12*r2;
            float rv2 = b20*r0 + b21*r1 + b22*r2;
            out[obase+0] = cons[n*3+0] + rv0;
            out[obase+1] = cons[n*3+1] + rv1;
            out[obase+2] = cons[n*3+2] + rv2;
            out[BATCH*NPTS*3 + obase+0] = rv0;
            out[BATCH*NPTS*3 + obase+1] = rv1;
            out[BATCH*NPTS*3 + obase+2] = rv2;
        }
    }
}

extern "C" void kernel_launch(void* const* d_in, const int* in_sizes, int n_in,
                              void* d_out, int out_size, void* d_ws, size_t ws_size,
                              hipStream_t stream)
{
    const float* z0     = (const float*)d_in[0];
    const float* cons   = (const float*)d_in[1];
    const float* w_lin0 = (const float*)d_in[2];
    const float* w_def  = (const float*)d_in[3];
    const float* w1a    = (const float*)d_in[4];
    const float* w1b    = (const float*)d_in[5];
    _Float16* W = (_Float16*)d_ws;   // 8 slots * 16384 f16 = 256 KB

    prep_weights_k<<<512, 256, 0, stream>>>(w_lin0, w_def, w1a, W);
    decoder_main<<<NPTS/8, 64, 0, stream>>>(z0, cons, W, w1b, (float*)d_out);
}

// Round 4
// 248.907 us; speedup vs baseline: 1.0443x; 1.0443x over previous
//
#include <hip/hip_runtime.h>
#include <hip/hip_bf16.h>
#include <math.h>

typedef _Float16 half8 __attribute__((ext_vector_type(8)));
typedef float    f32x4 __attribute__((ext_vector_type(4)));

#define NPTS  50000
#define BATCH 8

// ---------------- weight prep: fp32 -> f16, pi-permuted columns ----------------
// 8 slots of [128 rows o][128 positions pos]. pos=(ks,g,j):
//   k(pos) = ks*32 + 16*(j>>2) + 4*g + (j&3).
// Layer j's D-accumulator registers (after ELU+f16 pack) are directly the
// B-fragment of layer j+1 -- x never leaves registers (verified R2/R3).
// Slot 0: [pe60|pad4|z32|pad32]; 1..6: deform; 7: lin1a (3 rows used).
__global__ void prep_weights_k(const float* __restrict__ w_lin0,
                               const float* __restrict__ w_def,
                               const float* __restrict__ w1a,
                               _Float16* __restrict__ W)
{
    int idx = blockIdx.x * blockDim.x + threadIdx.x;
    if (idx >= 8*128*128) return;
    int slot = idx >> 14;
    int o    = (idx >> 7) & 127;
    int pos  = idx & 127;
    int ks = pos >> 5, l = pos & 31, gg = l >> 3, jj = l & 7;
    int k = ks*32 + 16*(jj>>2) + 4*gg + (jj&3);
    float v = 0.f;
    if (slot == 0) {
        if (k < 60)                 v = w_lin0[o*92 + k];
        else if (k >= 64 && k < 96) v = w_lin0[o*92 + 60 + (k-64)];
    } else if (slot <= 6) {
        v = w_def[(slot-1)*16384 + o*128 + k];
    } else {
        if (o < 3) v = w1a[o*128 + k];
    }
    W[idx] = (_Float16)v;
}

// ---- one layer: 4 ft-pairs; pack chunk p (ELU+cvt) fused right after pair p's
// MFMAs so it interleaves with pair p+1's loads+MFMAs. Bout[pt][p] = ks-slot p.
template<int NKS, bool DOELU>
__device__ __forceinline__ void layer_step(const unsigned char* __restrict__ Wl,
                                           const half8 (&Bin)[4][4],
                                           half8 (&Bout)[4][4],
                                           int voff)
{
    const f32x4 Z = {0.f, 0.f, 0.f, 0.f};
    half8 A[2][2][4];
    #pragma unroll
    for (int f = 0; f < 2; ++f)
        #pragma unroll
        for (int ks = 0; ks < NKS; ++ks)
            A[0][f][ks] = *(const half8*)(Wl + voff + f*4096 + ks*64);

    #pragma unroll
    for (int pr = 0; pr < 4; ++pr) {
        if (pr < 3) {   // prefetch pair pr+1's panels into the alternate buffer
            #pragma unroll
            for (int f = 0; f < 2; ++f)
                #pragma unroll
                for (int ks = 0; ks < NKS; ++ks)
                    A[(pr+1)&1][f][ks] =
                        *(const half8*)(Wl + voff + (2*(pr+1)+f)*4096 + ks*64);
        }
        f32x4 acc[4][2];
        #pragma unroll
        for (int f = 0; f < 2; ++f)
            #pragma unroll
            for (int pt = 0; pt < 4; ++pt) {
                acc[pt][f] = __builtin_amdgcn_mfma_f32_16x16x32_f16(
                    A[pr&1][f][0], Bin[pt][0], Z, 0, 0, 0);
                #pragma unroll
                for (int ks = 1; ks < NKS; ++ks)
                    acc[pt][f] = __builtin_amdgcn_mfma_f32_16x16x32_f16(
                        A[pr&1][f][ks], Bin[pt][ks], acc[pt][f], 0, 0, 0);
            }
        #pragma unroll
        for (int pt = 0; pt < 4; ++pt) {
            half8 h;
            #pragma unroll
            for (int e = 0; e < 4; ++e) {
                float v0 = acc[pt][0][e];
                float v1 = acc[pt][1][e];
                if (DOELU) {
                    v0 = (v0 > 0.f) ? v0 : (__expf(v0) - 1.f);
                    v1 = (v1 > 0.f) ? v1 : (__expf(v1) - 1.f);
                }
                h[e]   = (_Float16)v0;
                h[4+e] = (_Float16)v1;
            }
            Bout[pt][pr] = h;
        }
    }
}

// ---------------- fused decoder: no LDS, no barriers, 4 independent waves/block ----
__global__ __launch_bounds__(256, 2)
void decoder_main(const float* __restrict__ z0,
                  const float* __restrict__ cons,
                  const _Float16* __restrict__ W,
                  const float* __restrict__ w1b,
                  float* __restrict__ out)
{
    const int lane = threadIdx.x & 63;
    const int wid  = threadIdx.x >> 6;
    const int p = lane & 15;
    const int g = lane >> 4;
    const int n0 = blockIdx.x * 32 + wid * 8;    // 8 n-points per wave
    const int voff = p*256 + g*16;

    const f32x4 Z = {0.f, 0.f, 0.f, 0.f};

    // ---- build layer-0 B-fragments (pi-position order), K=96 -> ks 0..2 ----
    half8 B1[4][4], B2[4][4];
    #pragma unroll
    for (int pt = 0; pt < 4; ++pt) {
        const int lrow = pt*16 + p;
        int n = n0 + (lrow >> 3); if (n >= NPTS) n = NPTS - 1;
        const int b = lrow & 7;
        float c0 = cons[n*3+0], c1 = cons[n*3+1], c2 = cons[n*3+2];
        #pragma unroll
        for (int ks = 0; ks < 2; ++ks) {
            half8 h;
            #pragma unroll
            for (int j = 0; j < 8; ++j) {
                int k = ks*32 + 16*(j>>2) + 4*g + (j&3);
                float v = 0.f;
                if (k < 60) {
                    int c = k/20, rem = k%20, i = rem%10;
                    float f  = exp2f(7.f * (1.f - (float)i * (1.f/9.f)));
                    float cc = (c == 0) ? c0 : (c == 1) ? c1 : c2;
                    float a  = cc * f;
                    v = (rem < 10) ? __sinf(a) : __cosf(a);
                }
                h[j] = (_Float16)v;
            }
            B1[pt][ks] = h;
        }
        half8 hz;
        #pragma unroll
        for (int j = 0; j < 8; ++j)
            hz[j] = (_Float16)z0[b*32 + 16*(j>>2) + 4*g + (j&3)];
        B1[pt][2] = hz;
    }

    const unsigned char* Wb = (const unsigned char*)W;

    // ---- layer 0 (lin0, K=96, no ELU on output) ----
    layer_step<3, false>(Wb, B1, B2, voff);

    // ---- layers 1..6 (deform, ELU on output), 3 x 2-layer ping-pong ----
    #pragma unroll 1
    for (int jj = 0; jj < 3; ++jj) {
        layer_step<4, true>(Wb + (1 + 2*jj)*32768, B2, B1, voff);
        layer_step<4, true>(Wb + (2 + 2*jj)*32768, B1, B2, voff);
    }
    // final activations now in B2

    // ---- lin1a: 16 output rows (3 used), K=128 ----
    f32x4 a1[4];
    {
        const unsigned char* W7 = Wb + 7*32768;
        half8 A7[4];
        #pragma unroll
        for (int ks = 0; ks < 4; ++ks)
            A7[ks] = *(const half8*)(W7 + voff + ks*64);
        #pragma unroll
        for (int pt = 0; pt < 4; ++pt)
            a1[pt] = __builtin_amdgcn_mfma_f32_16x16x32_f16(A7[0], B2[pt][0], Z, 0, 0, 0);
        #pragma unroll
        for (int ks = 1; ks < 4; ++ks)
            #pragma unroll
            for (int pt = 0; pt < 4; ++pt)
                a1[pt] = __builtin_amdgcn_mfma_f32_16x16x32_f16(A7[ks], B2[pt][ks], a1[pt], 0, 0, 0);
    }

    // ---- ELU + lin1b (3x3) + stores, in-register (g==0 lanes own feats 0..3) ----
    if (g == 0) {
        float b00=w1b[0],b01=w1b[1],b02=w1b[2];
        float b10=w1b[3],b11=w1b[4],b12=w1b[5];
        float b20=w1b[6],b21=w1b[7],b22=w1b[8];
        #pragma unroll
        for (int pt = 0; pt < 4; ++pt) {
            int row = pt*16 + p;
            int n = n0 + (row >> 3);
            if (n < NPTS) {
                float r0 = a1[pt][0], r1 = a1[pt][1], r2 = a1[pt][2];
                r0 = (r0 > 0.f) ? r0 : (__expf(r0) - 1.f);
                r1 = (r1 > 0.f) ? r1 : (__expf(r1) - 1.f);
                r2 = (r2 > 0.f) ? r2 : (__expf(r2) - 1.f);
                int b = row & 7;
                int obase = (b*NPTS + n)*3;
                float rv0 = b00*r0 + b01*r1 + b02*r2;
                float rv1 = b10*r0 + b11*r1 + b12*r2;
                float rv2 = b20*r0 + b21*r1 + b22*r2;
                out[obase+0] = cons[n*3+0] + rv0;
                out[obase+1] = cons[n*3+1] + rv1;
                out[obase+2] = cons[n*3+2] + rv2;
                out[BATCH*NPTS*3 + obase+0] = rv0;
                out[BATCH*NPTS*3 + obase+1] = rv1;
                out[BATCH*NPTS*3 + obase+2] = rv2;
            }
        }
    }
}

extern "C" void kernel_launch(void* const* d_in, const int* in_sizes, int n_in,
                              void* d_out, int out_size, void* d_ws, size_t ws_size,
                              hipStream_t stream)
{
    const float* z0     = (const float*)d_in[0];
    const float* cons   = (const float*)d_in[1];
    const float* w_lin0 = (const float*)d_in[2];
    const float* w_def  = (const float*)d_in[3];
    const float* w1a    = (const float*)d_in[4];
    const float* w1b    = (const float*)d_in[5];
    _Float16* W = (_Float16*)d_ws;   // 8 slots * 16384 f16 = 256 KB

    prep_weights_k<<<512, 256, 0, stream>>>(w_lin0, w_def, w1a, W);
    int nblk = (NPTS + 31) / 32;     // 1563 (tail handled by clamp+guard)
    decoder_main<<<nblk, 256, 0, stream>>>(z0, cons, W, w1b, (float*)d_out);
}